// Round 1
// baseline (56591.083 us; speedup 1.0000x reference)
//
#include <hip/hip_runtime.h>
#include <math.h>

#define B_N 64
#define T_N 3072
#define FIN 128
#define TP 1024      // conv output length
#define COUT 64
#define HID 256
#define G4 1024      // 4*HID
#define OUT_N 10
#define NCHUNK 24
#define CHUNK_T (T_N / NCHUNK)   // 128

// ---------------------------------------------------------------------------
// Kernel 0: weight transposes / permutes so later loads are coalesced.
//  whhT[k][j] = w_hh[j][k]            (256 x 1024)
//  wihT[k][j] = w_ih[j][k]            (64 x 1024)
//  wc2[j][oc] = conv_w[oc][ic][kk],   j = kk*128 + ic   (384 x 64)
// ---------------------------------------------------------------------------
__global__ void prep_weights(const float* __restrict__ w_ih,
                             const float* __restrict__ w_hh,
                             const float* __restrict__ conv_w,
                             float* __restrict__ whhT,
                             float* __restrict__ wihT,
                             float* __restrict__ wc2) {
    int i = blockIdx.x * 256 + threadIdx.x;
    if (i < 262144) {                       // whhT
        int k = i >> 10, j = i & 1023;
        whhT[i] = w_hh[j * 256 + k];
        return;
    }
    int i2 = i - 262144;
    if (i2 < 65536) {                       // wihT
        int k = i2 >> 10, j = i2 & 1023;
        wihT[i2] = w_ih[j * 64 + k];
        return;
    }
    int i3 = i2 - 65536;
    if (i3 < 24576) {                       // wc2
        int j = i3 >> 6, oc = i3 & 63;
        int kk = j >> 7, ic = j & 127;
        wc2[i3] = conv_w[(oc * 128 + ic) * 3 + kk];
    }
}

// ---------------------------------------------------------------------------
// Kernel 1: partial sum-of-squares over time (for F.normalize along dim=1).
// part[b][chunk][f] = sum over 128 t-rows of input[b,t,f]^2
// ---------------------------------------------------------------------------
__global__ void norm_partial(const float* __restrict__ in, float* __restrict__ part) {
    int b = blockIdx.x, ch = blockIdx.y, f = threadIdx.x;
    const float* p = in + ((size_t)b * T_N + (size_t)ch * CHUNK_T) * FIN + f;
    float s0 = 0.f, s1 = 0.f, s2 = 0.f, s3 = 0.f;
#pragma unroll
    for (int r = 0; r < CHUNK_T; r += 4) {
        float v0 = p[(r + 0) * FIN];
        float v1 = p[(r + 1) * FIN];
        float v2 = p[(r + 2) * FIN];
        float v3 = p[(r + 3) * FIN];
        s0 += v0 * v0; s1 += v1 * v1; s2 += v2 * v2; s3 += v3 * v3;
    }
    part[(b * NCHUNK + ch) * FIN + f] = (s0 + s1) + (s2 + s3);
}

// ---------------------------------------------------------------------------
// Kernel 2: normalize + conv1d(k=3, stride=3) + bias + relu.
// Since stride==K, conv == GEMM: out[b,t',oc] = sum_j A[b,t'][j] * wc2[j][oc],
// A[b,t'][j] = in[b, 3t' + j/128, j%128] * invnorm[b, j%128], j in [0,384).
// Block: 256 threads = (oc in [0,64)) x (tq in [0,4)), 4 t' per thread.
// Grid: (64 b, 64 tiles of 16 t').
// ---------------------------------------------------------------------------
__global__ __launch_bounds__(256) void conv_relu(
        const float* __restrict__ in, const float* __restrict__ part,
        const float* __restrict__ wc2, const float* __restrict__ cb,
        float* __restrict__ X) {
    __shared__ __align__(16) float xs[16 * 384];   // 24 KB: 48 input rows, scaled
    __shared__ __align__(16) float wsh[96 * 64];   // 24 KB: one j-chunk of weights
    __shared__ float invn[FIN];

    int b = blockIdx.x, tile = blockIdx.y;
    int tid = threadIdx.x;

    if (tid < FIN) {
        float s = 0.f;
#pragma unroll
        for (int c = 0; c < NCHUNK; c++) s += part[(b * NCHUNK + c) * FIN + tid];
        invn[tid] = rsqrtf(fmaxf(s, 1e-24f));
    }
    __syncthreads();

    // stage 48 input rows, scaled. flat idx i = (3*tl+kk)*128+ic == tl*384 + j
    const float* ip = in + ((size_t)b * T_N + (size_t)tile * 48) * FIN;
    for (int i = tid; i < 6144; i += 256) xs[i] = ip[i] * invn[i & 127];

    int oc = tid & 63, tq = tid >> 6;
    float acc0 = 0.f, acc1 = 0.f, acc2 = 0.f, acc3 = 0.f;
    const float* xb = xs + tq * 4 * 384;

    for (int c = 0; c < 4; c++) {
        __syncthreads();
        for (int i = tid; i < 6144; i += 256) wsh[i] = wc2[c * 6144 + i];
        __syncthreads();
#pragma unroll 8
        for (int jj = 0; jj < 96; jj += 4) {
            int j = c * 96 + jj;
            float w0 = wsh[(jj + 0) * 64 + oc];
            float w1 = wsh[(jj + 1) * 64 + oc];
            float w2 = wsh[(jj + 2) * 64 + oc];
            float w3 = wsh[(jj + 3) * 64 + oc];
            float4 x0 = *(const float4*)(xb + j);
            float4 x1 = *(const float4*)(xb + 384 + j);
            float4 x2 = *(const float4*)(xb + 768 + j);
            float4 x3 = *(const float4*)(xb + 1152 + j);
            acc0 += w0 * x0.x + w1 * x0.y + w2 * x0.z + w3 * x0.w;
            acc1 += w0 * x1.x + w1 * x1.y + w2 * x1.z + w3 * x1.w;
            acc2 += w0 * x2.x + w1 * x2.y + w2 * x2.z + w3 * x2.w;
            acc3 += w0 * x3.x + w1 * x3.y + w2 * x3.z + w3 * x3.w;
        }
    }
    float bb = cb[oc];
    int tp0 = tile * 16 + tq * 4;
    size_t o = ((size_t)b * TP + tp0) * COUT + oc;
    X[o]       = fmaxf(acc0 + bb, 0.f);
    X[o + 64]  = fmaxf(acc1 + bb, 0.f);
    X[o + 128] = fmaxf(acc2 + bb, 0.f);
    X[o + 192] = fmaxf(acc3 + bb, 0.f);
}

// ---------------------------------------------------------------------------
// Kernel 3: persistent LSTM. One workgroup per batch (batches are independent
// through the recurrence -> no cross-WG sync ever). 1024 threads; thread j
// owns gate column j and keeps its 320 weights resident in VGPR+AGPR
// (unified 512-reg/thread budget at 4 waves/SIMD). h broadcast via LDS.
// ---------------------------------------------------------------------------
__device__ __forceinline__ float fsig(float x) {
    return 1.f / (1.f + __expf(-x));
}
__device__ __forceinline__ float ftanh(float x) {
    float xc = fminf(fmaxf(x, -15.f), 15.f);
    float e = __expf(2.f * xc);
    return (e - 1.f) / (e + 1.f);
}

__global__ __launch_bounds__(1024) void lstm_kernel(
        const float* __restrict__ X, const float* __restrict__ whhT,
        const float* __restrict__ wihT,
        const float* __restrict__ b_ih, const float* __restrict__ b_hh,
        const float* __restrict__ hx0, const float* __restrict__ cx0,
        const float* __restrict__ lin_w, const float* __restrict__ lin_b,
        float* __restrict__ out) {
    const int b = blockIdx.x;
    const int j = threadIdx.x;          // gate column 0..1023

    __shared__ __align__(16) float h_s[HID];
    __shared__ __align__(16) float x_s[COUT];
    __shared__ float gates_s[G4];

    // resident weights: w_hh row j (256) + w_ih row j (64), coalesced loads
    float wh[HID];
#pragma unroll
    for (int k = 0; k < HID; k++) wh[k] = whhT[(size_t)k * G4 + j];
    float wi[COUT];
#pragma unroll
    for (int k = 0; k < COUT; k++) wi[k] = wihT[(size_t)k * G4 + j];
    const float bias = b_ih[j] + b_hh[j];

    float c = 0.f;
    if (j < HID) {
        c = cx0[b * HID + j];
        h_s[j] = hx0[b * HID + j];
    }
    const float* Xb = X + (size_t)b * TP * COUT;
    if (j < COUT) x_s[j] = Xb[j];
    __syncthreads();

    for (int t = 0; t < TP; t++) {
        // wave 4 (threads 256..319) prefetches next step's x into registers
        float xnext = 0.f;
        if (j >= 256 && j < 320 && t < TP - 1) xnext = Xb[(t + 1) * COUT + (j - 256)];

        float a0 = bias, a1 = 0.f, a2 = 0.f, a3 = 0.f;
#pragma unroll
        for (int k = 0; k < HID; k += 16) {
            float4 h0 = *(const float4*)(h_s + k);
            float4 h1 = *(const float4*)(h_s + k + 4);
            float4 h2 = *(const float4*)(h_s + k + 8);
            float4 h3 = *(const float4*)(h_s + k + 12);
            a0 += wh[k + 0] * h0.x + wh[k + 1] * h0.y + wh[k + 2] * h0.z + wh[k + 3] * h0.w;
            a1 += wh[k + 4] * h1.x + wh[k + 5] * h1.y + wh[k + 6] * h1.z + wh[k + 7] * h1.w;
            a2 += wh[k + 8] * h2.x + wh[k + 9] * h2.y + wh[k + 10] * h2.z + wh[k + 11] * h2.w;
            a3 += wh[k + 12] * h3.x + wh[k + 13] * h3.y + wh[k + 14] * h3.z + wh[k + 15] * h3.w;
        }
#pragma unroll
        for (int k = 0; k < COUT; k += 16) {
            float4 x0 = *(const float4*)(x_s + k);
            float4 x1 = *(const float4*)(x_s + k + 4);
            float4 x2 = *(const float4*)(x_s + k + 8);
            float4 x3 = *(const float4*)(x_s + k + 12);
            a0 += wi[k + 0] * x0.x + wi[k + 1] * x0.y + wi[k + 2] * x0.z + wi[k + 3] * x0.w;
            a1 += wi[k + 4] * x1.x + wi[k + 5] * x1.y + wi[k + 6] * x1.z + wi[k + 7] * x1.w;
            a2 += wi[k + 8] * x2.x + wi[k + 9] * x2.y + wi[k + 10] * x2.z + wi[k + 11] * x2.w;
            a3 += wi[k + 12] * x3.x + wi[k + 13] * x3.y + wi[k + 14] * x3.z + wi[k + 15] * x3.w;
        }
        float g = (a0 + a1) + (a2 + a3);
        gates_s[j] = g;
        __syncthreads();

        if (j < HID) {
            // this thread's g IS the i-gate for h-column j
            float fg = gates_s[j + 256];
            float gg = gates_s[j + 512];
            float og = gates_s[j + 768];
            c = fsig(fg) * c + fsig(g) * ftanh(gg);
            h_s[j] = fsig(og) * ftanh(c);
        } else if (j < 320) {
            x_s[j - 256] = xnext;
        }
        __syncthreads();
    }

    // epilogue: out[b] = h @ lin_w.T + lin_b
    if (j < OUT_N) {
        float s = lin_b[j];
#pragma unroll 4
        for (int k = 0; k < HID; k++) s += h_s[k] * lin_w[j * HID + k];
        out[b * OUT_N + j] = s;
    }
}

// ---------------------------------------------------------------------------
extern "C" void kernel_launch(void* const* d_in, const int* in_sizes, int n_in,
                              void* d_out, int out_size, void* d_ws, size_t ws_size,
                              hipStream_t stream) {
    const float* input  = (const float*)d_in[0];
    // d_in[1] = r (unused by reference)
    const float* hx0    = (const float*)d_in[2];
    const float* cx0    = (const float*)d_in[3];
    const float* conv_w = (const float*)d_in[4];
    const float* conv_b = (const float*)d_in[5];
    const float* w_ih   = (const float*)d_in[6];
    const float* b_ih   = (const float*)d_in[7];
    const float* w_hh   = (const float*)d_in[8];
    const float* b_hh   = (const float*)d_in[9];
    const float* lin_w  = (const float*)d_in[10];
    const float* lin_b  = (const float*)d_in[11];

    float* ws   = (float*)d_ws;
    float* part = ws;                  // 64*24*128        = 196608
    float* whhT = ws + 196608;         // 256*1024         = 262144
    float* wihT = ws + 458752;         // 64*1024          =  65536
    float* wc2  = ws + 524288;         // 384*64           =  24576
    float* X    = ws + 548864;         // 64*1024*64       = 4194304

    prep_weights<<<1376, 256, 0, stream>>>(w_ih, w_hh, conv_w, whhT, wihT, wc2);
    norm_partial<<<dim3(B_N, NCHUNK), FIN, 0, stream>>>(input, part);
    conv_relu<<<dim3(B_N, 64), 256, 0, stream>>>(input, part, wc2, conv_b, X);
    lstm_kernel<<<B_N, 1024, 0, stream>>>(X, whhT, wihT, b_ih, b_hh, hx0, cx0,
                                          lin_w, lin_b, (float*)d_out);
}

// Round 2
// 3256.110 us; speedup vs baseline: 17.3800x; 17.3800x over previous
//
#include <hip/hip_runtime.h>
#include <math.h>

#define B_N 64
#define T_N 3072
#define FIN 128
#define TP 1024      // conv output length
#define COUT 64
#define HID 256
#define G4 1024      // 4*HID
#define OUT_N 10
#define NCHUNK 24
#define CHUNK_T (T_N / NCHUNK)   // 128

// LSTM weight partition (per gate-column, in packed f16x2 dwords; 128 total for w_hh)
#define RREG 60     // dwords 0..59   -> VGPRs
#define RLDS 9      // uint4 chunks: dwords 60..95 -> LDS
#define RSTR 8      // uint4 chunks: dwords 96..127 -> streamed from L2 each step

typedef _Float16 h2_t __attribute__((ext_vector_type(2)));

#if defined(__has_builtin)
#if __has_builtin(__builtin_amdgcn_fdot2)
#define HAVE_FDOT2 1
#endif
#endif

__device__ __forceinline__ float fdot2(unsigned w, unsigned h, float acc) {
#ifdef HAVE_FDOT2
    return __builtin_amdgcn_fdot2(__builtin_bit_cast(h2_t, w),
                                  __builtin_bit_cast(h2_t, h), acc, false);
#else
    h2_t wv = __builtin_bit_cast(h2_t, w), hv = __builtin_bit_cast(h2_t, h);
    return acc + (float)wv.x * (float)hv.x + (float)wv.y * (float)hv.y;
#endif
}

__device__ __forceinline__ unsigned pack2(float a, float b) {
    unsigned la = (unsigned)__builtin_bit_cast(unsigned short, (_Float16)a);
    unsigned lb = (unsigned)__builtin_bit_cast(unsigned short, (_Float16)b);
    return la | (lb << 16);
}

// ---------------------------------------------------------------------------
// Pack LSTM weights to f16x2 in the layouts the LSTM kernel consumes.
// grid 1024 (j = gate col), 128 threads (d = packed dword index).
// ---------------------------------------------------------------------------
__global__ void pack_weights(const float* __restrict__ w_ih,
                             const float* __restrict__ w_hh,
                             unsigned* __restrict__ whhR,   // [60][1024]
                             unsigned* __restrict__ whhL,   // uint4 [9][1024] flat dwords
                             unsigned* __restrict__ whhS,   // uint4 [8][1024] flat dwords
                             unsigned* __restrict__ wihR) { // [32][1024]
    int j = blockIdx.x, d = threadIdx.x;   // d in [0,128)
    const float* wr = w_hh + j * HID;
    unsigned p = pack2(wr[2 * d], wr[2 * d + 1]);
    if (d < RREG) {
        whhR[d * 1024 + j] = p;
    } else if (d < RREG + 4 * RLDS) {
        int dd = d - RREG;
        whhL[((dd >> 2) * 1024 + j) * 4 + (dd & 3)] = p;
    } else {
        int dd = d - (RREG + 4 * RLDS);
        whhS[((dd >> 2) * 1024 + j) * 4 + (dd & 3)] = p;
    }
    if (d < 32) {
        wihR[d * 1024 + j] = pack2(w_ih[j * COUT + 2 * d], w_ih[j * COUT + 2 * d + 1]);
    }
}

// conv weight permute: wc2[j][oc], j = kk*128+ic
__global__ void prep_conv_w(const float* __restrict__ conv_w, float* __restrict__ wc2) {
    int i = blockIdx.x * 256 + threadIdx.x;
    if (i < 24576) {
        int j = i >> 6, oc = i & 63;
        int kk = j >> 7, ic = j & 127;
        wc2[i] = conv_w[(oc * 128 + ic) * 3 + kk];
    }
}

// ---------------------------------------------------------------------------
// partial sum-of-squares over time (F.normalize along dim=1)
// ---------------------------------------------------------------------------
__global__ void norm_partial(const float* __restrict__ in, float* __restrict__ part) {
    int b = blockIdx.x, ch = blockIdx.y, f = threadIdx.x;
    const float* p = in + ((size_t)b * T_N + (size_t)ch * CHUNK_T) * FIN + f;
    float s0 = 0.f, s1 = 0.f, s2 = 0.f, s3 = 0.f;
#pragma unroll
    for (int r = 0; r < CHUNK_T; r += 4) {
        float v0 = p[(r + 0) * FIN];
        float v1 = p[(r + 1) * FIN];
        float v2 = p[(r + 2) * FIN];
        float v3 = p[(r + 3) * FIN];
        s0 += v0 * v0; s1 += v1 * v1; s2 += v2 * v2; s3 += v3 * v3;
    }
    part[(b * NCHUNK + ch) * FIN + f] = (s0 + s1) + (s2 + s3);
}

// ---------------------------------------------------------------------------
// normalize + conv1d(k=3,stride=3) + bias + relu  (stride==K -> GEMM)
// ---------------------------------------------------------------------------
__global__ __launch_bounds__(256) void conv_relu(
        const float* __restrict__ in, const float* __restrict__ part,
        const float* __restrict__ wc2, const float* __restrict__ cb,
        float* __restrict__ X) {
    __shared__ __align__(16) float xs[16 * 384];
    __shared__ __align__(16) float wsh[96 * 64];
    __shared__ float invn[FIN];

    int b = blockIdx.x, tile = blockIdx.y;
    int tid = threadIdx.x;

    if (tid < FIN) {
        float s = 0.f;
#pragma unroll
        for (int c = 0; c < NCHUNK; c++) s += part[(b * NCHUNK + c) * FIN + tid];
        invn[tid] = rsqrtf(fmaxf(s, 1e-24f));
    }
    __syncthreads();

    const float* ip = in + ((size_t)b * T_N + (size_t)tile * 48) * FIN;
    for (int i = tid; i < 6144; i += 256) xs[i] = ip[i] * invn[i & 127];

    int oc = tid & 63, tq = tid >> 6;
    float acc0 = 0.f, acc1 = 0.f, acc2 = 0.f, acc3 = 0.f;
    const float* xb = xs + tq * 4 * 384;

    for (int c = 0; c < 4; c++) {
        __syncthreads();
        for (int i = tid; i < 6144; i += 256) wsh[i] = wc2[c * 6144 + i];
        __syncthreads();
#pragma unroll 8
        for (int jj = 0; jj < 96; jj += 4) {
            int j = c * 96 + jj;
            float w0 = wsh[(jj + 0) * 64 + oc];
            float w1 = wsh[(jj + 1) * 64 + oc];
            float w2 = wsh[(jj + 2) * 64 + oc];
            float w3 = wsh[(jj + 3) * 64 + oc];
            float4 x0 = *(const float4*)(xb + j);
            float4 x1 = *(const float4*)(xb + 384 + j);
            float4 x2 = *(const float4*)(xb + 768 + j);
            float4 x3 = *(const float4*)(xb + 1152 + j);
            acc0 += w0 * x0.x + w1 * x0.y + w2 * x0.z + w3 * x0.w;
            acc1 += w0 * x1.x + w1 * x1.y + w2 * x1.z + w3 * x1.w;
            acc2 += w0 * x2.x + w1 * x2.y + w2 * x2.z + w3 * x2.w;
            acc3 += w0 * x3.x + w1 * x3.y + w2 * x3.z + w3 * x3.w;
        }
    }
    float bb = cb[oc];
    int tp0 = tile * 16 + tq * 4;
    size_t o = ((size_t)b * TP + tp0) * COUT + oc;
    X[o]       = fmaxf(acc0 + bb, 0.f);
    X[o + 64]  = fmaxf(acc1 + bb, 0.f);
    X[o + 128] = fmaxf(acc2 + bb, 0.f);
    X[o + 192] = fmaxf(acc3 + bb, 0.f);
}

// ---------------------------------------------------------------------------
// Persistent LSTM: 64 blocks (one batch each) x 512 threads.
// Thread j owns gate cols j (i or f) and j+512 (g or o).
// w_hh f16x2: 60 dwords/col in VGPRs, 36 in LDS, 32 streamed from L2/step.
// w_ih f16x2: 32 dwords/col in VGPRs. h in LDS f16; c/gates fp32.
// ---------------------------------------------------------------------------
__device__ __forceinline__ float fsig(float x) {
    return 1.f / (1.f + __expf(-x));
}
__device__ __forceinline__ float ftanh(float x) {
    float xc = fminf(fmaxf(x, -15.f), 15.f);
    float e = __expf(2.f * xc);
    return (e - 1.f) / (e + 1.f);
}

#define SMEM_WL   0
#define SMEM_H    147456
#define SMEM_X    147968
#define SMEM_FO   148096
#define SMEM_H32  150144
#define SMEM_SIZE 151168

#define DOTP(wa, wb, hw) do { a0 = fdot2((wa), (hw), a0); a1 = fdot2((wb), (hw), a1); } while (0)
#define DOTC4(WA, WB, H) do { DOTP((WA).x,(WB).x,(H).x); DOTP((WA).y,(WB).y,(H).y); \
                              DOTP((WA).z,(WB).z,(H).z); DOTP((WA).w,(WB).w,(H).w); } while (0)

__global__ __launch_bounds__(512) void lstm_kernel(
        const float* __restrict__ X,
        const unsigned* __restrict__ whhR, const uint4* __restrict__ whhL4,
        const uint4* __restrict__ whhS4, const unsigned* __restrict__ wihR,
        const float* __restrict__ b_ih, const float* __restrict__ b_hh,
        const float* __restrict__ hx0, const float* __restrict__ cx0,
        const float* __restrict__ lin_w, const float* __restrict__ lin_b,
        float* __restrict__ out) {
    extern __shared__ char smem[];
    uint4*     wL    = (uint4*)(smem + SMEM_WL);      // [9][1024] uint4
    _Float16*  h_s   = (_Float16*)(smem + SMEM_H);    // 256
    _Float16*  x_s   = (_Float16*)(smem + SMEM_X);    // 64
    float2*    fo_s  = (float2*)(smem + SMEM_FO);     // 256
    float*     h32_s = (float*)(smem + SMEM_H32);     // 256

    const int b = blockIdx.x, j = threadIdx.x;
    const int jb = j + 512;

    // ---- init: register-resident weights (coalesced loads) ----
    unsigned wA[RREG], wB[RREG], iA[32], iB[32];
#pragma unroll
    for (int d = 0; d < RREG; d++) { wA[d] = whhR[d * 1024 + j]; wB[d] = whhR[d * 1024 + jb]; }
#pragma unroll
    for (int d = 0; d < 32; d++) { iA[d] = wihR[d * 1024 + j]; iB[d] = wihR[d * 1024 + jb]; }
    const float bias0 = b_ih[j] + b_hh[j];
    const float bias1 = b_ih[jb] + b_hh[jb];

    // ---- stage LDS-resident weight slice ----
    for (int i = j; i < RLDS * 1024; i += 512) wL[i] = whhL4[i];

    float c_reg = 0.f;
    if (j < HID) {
        c_reg = cx0[b * HID + j];
        h_s[j] = (_Float16)hx0[b * HID + j];
    }
    const float* Xb = X + (size_t)b * (TP * COUT);
    if (j < COUT) x_s[j] = (_Float16)Xb[j];
    __syncthreads();

    const uint4* hs4 = (const uint4*)h_s;   // 32 chunks of 8 h-values
    const uint4* xs4 = (const uint4*)x_s;   // 8 chunks
    const uint4* sA = whhS4 + j;
    const uint4* sB = whhS4 + jb;

    for (int t = 0; t < TP; t++) {
        float xn = 0.f;
        if (j < COUT && t != TP - 1) xn = Xb[(t + 1) * COUT + j];

        // phase-A streamed weights (h dwords 96..111), constant data -> prefetch
        uint4 pa0 = sA[0 * 1024], pa1 = sA[1 * 1024], pa2 = sA[2 * 1024], pa3 = sA[3 * 1024];
        uint4 pb0 = sB[0 * 1024], pb1 = sB[1 * 1024], pb2 = sB[2 * 1024], pb3 = sB[3 * 1024];

        float a0 = bias0, a1 = bias1;

        // register part: h chunks 0..14
#pragma unroll
        for (int d4 = 0; d4 < 15; d4++) {
            uint4 H = hs4[d4];
            DOTP(wA[4 * d4 + 0], wB[4 * d4 + 0], H.x);
            DOTP(wA[4 * d4 + 1], wB[4 * d4 + 1], H.y);
            DOTP(wA[4 * d4 + 2], wB[4 * d4 + 2], H.z);
            DOTP(wA[4 * d4 + 3], wB[4 * d4 + 3], H.w);
        }
        // LDS part: h chunks 15..23
#pragma unroll
        for (int d4 = 0; d4 < RLDS; d4++) {
            uint4 WA = wL[d4 * 1024 + j];
            uint4 WB = wL[d4 * 1024 + jb];
            uint4 H = hs4[15 + d4];
            DOTC4(WA, WB, H);
        }
        // consume phase-A: h chunks 24..27
        { uint4 H = hs4[24]; DOTC4(pa0, pb0, H); }
        { uint4 H = hs4[25]; DOTC4(pa1, pb1, H); }
        { uint4 H = hs4[26]; DOTC4(pa2, pb2, H); }
        { uint4 H = hs4[27]; DOTC4(pa3, pb3, H); }
        // phase-B streamed (h dwords 112..127)
        uint4 qa0 = sA[4 * 1024], qa1 = sA[5 * 1024], qa2 = sA[6 * 1024], qa3 = sA[7 * 1024];
        uint4 qb0 = sB[4 * 1024], qb1 = sB[5 * 1024], qb2 = sB[6 * 1024], qb3 = sB[7 * 1024];
        // x part: chunks 0..7 (covers phase-B latency)
#pragma unroll
        for (int d4 = 0; d4 < 8; d4++) {
            uint4 H = xs4[d4];
            DOTP(iA[4 * d4 + 0], iB[4 * d4 + 0], H.x);
            DOTP(iA[4 * d4 + 1], iB[4 * d4 + 1], H.y);
            DOTP(iA[4 * d4 + 2], iB[4 * d4 + 2], H.z);
            DOTP(iA[4 * d4 + 3], iB[4 * d4 + 3], H.w);
        }
        // consume phase-B: h chunks 28..31
        { uint4 H = hs4[28]; DOTC4(qa0, qb0, H); }
        { uint4 H = hs4[29]; DOTC4(qa1, qb1, H); }
        { uint4 H = hs4[30]; DOTC4(qa2, qb2, H); }
        { uint4 H = hs4[31]; DOTC4(qa3, qb3, H); }

        if (j >= HID) fo_s[j - HID] = make_float2(a0, a1);   // f, o
        __syncthreads();
        if (j < HID) {
            float2 fo = fo_s[j];
            float ig = fsig(a0), gg = ftanh(a1);
            float fg = fsig(fo.x), og = fsig(fo.y);
            c_reg = fg * c_reg + ig * gg;
            float hh = og * ftanh(c_reg);
            h_s[j] = (_Float16)hh;
            if (t == TP - 1) h32_s[j] = hh;
        }
        if (j < COUT) x_s[j] = (_Float16)xn;
        __syncthreads();
    }

    // epilogue: out[b] = h @ lin_w.T + lin_b  (fp32 h)
    if (j < OUT_N) {
        float s = lin_b[j];
        const float* lw = lin_w + j * HID;
#pragma unroll 4
        for (int k = 0; k < HID; k++) s += h32_s[k] * lw[k];
        out[b * OUT_N + j] = s;
    }
}

// ---------------------------------------------------------------------------
extern "C" void kernel_launch(void* const* d_in, const int* in_sizes, int n_in,
                              void* d_out, int out_size, void* d_ws, size_t ws_size,
                              hipStream_t stream) {
    const float* input  = (const float*)d_in[0];
    // d_in[1] = r (unused)
    const float* hx0    = (const float*)d_in[2];
    const float* cx0    = (const float*)d_in[3];
    const float* conv_w = (const float*)d_in[4];
    const float* conv_b = (const float*)d_in[5];
    const float* w_ih   = (const float*)d_in[6];
    const float* b_ih   = (const float*)d_in[7];
    const float* w_hh   = (const float*)d_in[8];
    const float* b_hh   = (const float*)d_in[9];
    const float* lin_w  = (const float*)d_in[10];
    const float* lin_b  = (const float*)d_in[11];

    float* ws = (float*)d_ws;
    float*    part  = ws;                          // 196608 floats
    float*    X     = ws + 196608;                 // 4194304 floats
    float*    wc2   = ws + 196608 + 4194304;       // 24576
    unsigned* whhR  = (unsigned*)(wc2 + 24576);    // 60*1024
    unsigned* whhL  = whhR + 60 * 1024;            // 36*1024 (uint4 [9][1024])
    unsigned* whhS  = whhL + 36 * 1024;            // 32*1024 (uint4 [8][1024])
    unsigned* wihR  = whhS + 32 * 1024;            // 32*1024

    (void)hipFuncSetAttribute((const void*)lstm_kernel,
                              hipFuncAttributeMaxDynamicSharedMemorySize, SMEM_SIZE);

    pack_weights<<<1024, 128, 0, stream>>>(w_ih, w_hh, whhR, whhL, whhS, wihR);
    prep_conv_w<<<96, 256, 0, stream>>>(conv_w, wc2);
    norm_partial<<<dim3(B_N, NCHUNK), FIN, 0, stream>>>(input, part);
    conv_relu<<<dim3(B_N, 64), 256, 0, stream>>>(input, part, wc2, conv_b, X);
    lstm_kernel<<<B_N, 512, SMEM_SIZE, stream>>>(
        X, whhR, (const uint4*)whhL, (const uint4*)whhS, wihR,
        b_ih, b_hh, hx0, cx0, lin_w, lin_b, (float*)d_out);
}